// Round 2
// baseline (750.058 us; speedup 1.0000x reference)
//
#include <hip/hip_runtime.h>

typedef __attribute__((ext_vector_type(8))) short short8;
typedef __attribute__((ext_vector_type(4))) float f32x4;

// bf16 weight workspace layout (element offsets)
#define OFF_WX 0         // [256][512]
#define OFF_W1 131072    // [112][512]  (real 100x512)
#define OFF_W2 188416    // [112][128]  (real 100x100)
#define OFF_W3 202752    // [112][128]  (real 100x100)
#define OFF_W4 217088    // [ 64][128]  (real  50x100)
#define OFF_W5 225280    // [256][ 64]  (real 256x50)
#define W_TOTAL 241664   // bf16 elements

static __device__ __forceinline__ unsigned short f2bf(float f) {
    unsigned int u = __builtin_bit_cast(unsigned int, f);
    unsigned int r = (u + 0x7fffu + ((u >> 16) & 1u)) >> 16;
    return (unsigned short)r;
}
static __device__ __forceinline__ float bf2f(unsigned short h) {
    unsigned int u = ((unsigned int)h) << 16;
    return __builtin_bit_cast(float, u);
}
static __device__ __forceinline__ float sigmoidf(float z) {
    return 1.f / (1.f + __expf(-z));
}

// ---------------- prep: fp32 weights -> padded bf16 in ws; zero hidden accum ----
__global__ __launch_bounds__(256) void prep_kernel(
    const float* __restrict__ wx, const float* __restrict__ wm1,
    const float* __restrict__ wm2, const float* __restrict__ wm3,
    const float* __restrict__ wm4, const float* __restrict__ wm5,
    unsigned short* __restrict__ wb, float* __restrict__ hid)
{
    const int stride = gridDim.x * blockDim.x;
    for (int idx = blockIdx.x * blockDim.x + threadIdx.x; idx < W_TOTAL; idx += stride) {
        float v;
        if (idx < OFF_W1) {
            v = wx[idx];                                      // exact 256x512
        } else if (idx < OFF_W2) {
            int j = idx - OFF_W1; int n = j >> 9, k = j & 511;
            v = (n < 100) ? wm1[n * 512 + k] : 0.f;
        } else if (idx < OFF_W3) {
            int j = idx - OFF_W2; int n = j >> 7, k = j & 127;
            v = (n < 100 && k < 100) ? wm2[n * 100 + k] : 0.f;
        } else if (idx < OFF_W4) {
            int j = idx - OFF_W3; int n = j >> 7, k = j & 127;
            v = (n < 100 && k < 100) ? wm3[n * 100 + k] : 0.f;
        } else if (idx < OFF_W5) {
            int j = idx - OFF_W4; int n = j >> 7, k = j & 127;
            v = (n < 50 && k < 100) ? wm4[n * 100 + k] : 0.f;
        } else {
            int j = idx - OFF_W5; int n = j >> 6, k = j & 63;
            v = (k < 50) ? wm5[n * 50 + k] : 0.f;
        }
        wb[idx] = f2bf(v);
    }
    for (int idx = blockIdx.x * blockDim.x + threadIdx.x; idx < 65536; idx += stride)
        hid[idx] = 0.f;
}

// ---------------- generic MFMA stage: LDS A [64][APITCH] x global bf16 W [NT*16][KPAD]
// N-tiles split across the 4 waves (wave w owns nt = w, w+4, ...). Each wave does all
// 4 m-tiles (64 rows). Epilogue called per (nt, mt) with the f32x4 accumulator.
template<int KPAD, int NT, int APITCH, typename Epi>
static __device__ __forceinline__ void stage(const unsigned short* As,
                                             const unsigned short* __restrict__ Wg,
                                             int wave, int lane, Epi&& epi)
{
    constexpr int NI = (NT + 3) >> 2;
    f32x4 acc[NI][4];
#pragma unroll
    for (int i = 0; i < NI; i++)
#pragma unroll
        for (int mt = 0; mt < 4; mt++)
            acc[i][mt] = {0.f, 0.f, 0.f, 0.f};

    const int kp  = (lane >> 4) << 3;   // k sub-offset within frag: 0/8/16/24
    const int l15 = lane & 15;

#pragma unroll 4
    for (int k0 = 0; k0 < KPAD; k0 += 32) {
        short8 af[4];
#pragma unroll
        for (int mt = 0; mt < 4; mt++)
            af[mt] = *(const short8*)(As + (mt * 16 + l15) * APITCH + k0 + kp);
#pragma unroll
        for (int i = 0; i < NI; i++) {
            const int nt = wave + (i << 2);
            if (nt < NT) {
                short8 bf = *(const short8*)(Wg + (nt * 16 + l15) * KPAD + k0 + kp);
#pragma unroll
                for (int mt = 0; mt < 4; mt++)
                    acc[i][mt] = __builtin_amdgcn_mfma_f32_16x16x32_bf16(
                        af[mt], bf, acc[i][mt], 0, 0, 0);
            }
        }
    }
#pragma unroll
    for (int i = 0; i < NI; i++) {
        const int nt = wave + (i << 2);
        if (nt < NT) {
#pragma unroll
            for (int mt = 0; mt < 4; mt++)
                epi(nt, mt, acc[i][mt]);
        }
    }
}

// ---------------- main fused kernel: block = (batch b, 64 timesteps t0..t0+63) ----
__global__ __launch_bounds__(256) void srnn_main(
    const float* __restrict__ x,
    const float* __restrict__ b1, const float* __restrict__ b2,
    const float* __restrict__ b3, const float* __restrict__ b4,
    const float* __restrict__ b5, const float* __restrict__ bx,
    const unsigned short* __restrict__ wb, float* __restrict__ hid)
{
    __shared__ __align__(16) unsigned short Xs[64 * 520];       // x tile, bf16, pitch 520
    __shared__ __align__(16) unsigned short ABuf[2 * 64 * 136]; // ping-pong acts, pitch 136
    __shared__ __align__(16) unsigned short Fxs[64 * 264];      // sigmoid(m5), pitch 264
    unsigned short* A1 = ABuf;
    unsigned short* A2 = ABuf + 64 * 136;
    unsigned short* Gs = ABuf;   // gate tile, pitch 264 (reuses A1+A2 after m5)

    const int tid  = threadIdx.x;
    const int wave = tid >> 6, lane = tid & 63;
    const int blk  = blockIdx.x;
    const int b    = blk >> 3;
    const int t0   = (blk & 7) << 6;
    const int l15  = lane & 15;
    const int rbase = (lane >> 4) << 2;

    // ---- stage x tile (64 rows x 512 fp32 -> bf16 LDS); zero ABuf (pads must be 0)
    for (int f = tid; f < 64 * 128; f += 256) {
        int m = f >> 7, c4 = f & 127;
        const float4* src = (const float4*)(x + ((size_t)(t0 + m) * 256 + b) * 512);
        float4 v = src[c4];
        unsigned int p0 = (unsigned int)f2bf(v.x) | ((unsigned int)f2bf(v.y) << 16);
        unsigned int p1 = (unsigned int)f2bf(v.z) | ((unsigned int)f2bf(v.w) << 16);
        *(uint2*)&Xs[m * 520 + (c4 << 2)] = make_uint2(p0, p1);
    }
    for (int i = tid; i < (2 * 64 * 136) / 4; i += 256)
        ((uint2*)ABuf)[i] = make_uint2(0u, 0u);
    __syncthreads();

    // ---- m1: x[64x512] @ w1^T -> relu -> A1 [64x128] (cols 100..111 zeroed, 112..127 pre-zeroed)
    stage<512, 7, 520>(Xs, wb + OFF_W1, wave, lane, [&](int nt, int mt, f32x4 v) {
        int c = nt * 16 + l15, r = mt * 16 + rbase;
        float bb = (c < 100) ? b1[c] : 0.f;
#pragma unroll
        for (int q = 0; q < 4; q++) {
            float val = (c < 100) ? fmaxf(v[q] + bb, 0.f) : 0.f;
            A1[(r + q) * 136 + c] = f2bf(val);
        }
    });
    __syncthreads();

    // ---- m2: A1 @ w2^T -> relu -> A2
    stage<128, 7, 136>(A1, wb + OFF_W2, wave, lane, [&](int nt, int mt, f32x4 v) {
        int c = nt * 16 + l15, r = mt * 16 + rbase;
        float bb = (c < 100) ? b2[c] : 0.f;
#pragma unroll
        for (int q = 0; q < 4; q++) {
            float val = (c < 100) ? fmaxf(v[q] + bb, 0.f) : 0.f;
            A2[(r + q) * 136 + c] = f2bf(val);
        }
    });
    __syncthreads();

    // ---- m3: A2 @ w3^T -> relu -> A1
    stage<128, 7, 136>(A2, wb + OFF_W3, wave, lane, [&](int nt, int mt, f32x4 v) {
        int c = nt * 16 + l15, r = mt * 16 + rbase;
        float bb = (c < 100) ? b3[c] : 0.f;
#pragma unroll
        for (int q = 0; q < 4; q++) {
            float val = (c < 100) ? fmaxf(v[q] + bb, 0.f) : 0.f;
            A1[(r + q) * 136 + c] = f2bf(val);
        }
    });
    __syncthreads();

    // ---- m4: A1 @ w4^T -> relu -> A2 cols 0..63 (real 50)
    stage<128, 4, 136>(A1, wb + OFF_W4, wave, lane, [&](int nt, int mt, f32x4 v) {
        int c = nt * 16 + l15, r = mt * 16 + rbase;
        float bb = (c < 50) ? b4[c] : 0.f;
#pragma unroll
        for (int q = 0; q < 4; q++) {
            float val = (c < 50) ? fmaxf(v[q] + bb, 0.f) : 0.f;
            A2[(r + q) * 136 + c] = f2bf(val);
        }
    });
    __syncthreads();

    // ---- m5: A2(K=64) @ w5^T -> sigmoid -> Fxs [64x256]
    stage<64, 16, 136>(A2, wb + OFF_W5, wave, lane, [&](int nt, int mt, f32x4 v) {
        int c = nt * 16 + l15, r = mt * 16 + rbase;
        float bb = b5[c];
#pragma unroll
        for (int q = 0; q < 4; q++)
            Fxs[(r + q) * 264 + c] = f2bf(sigmoidf(v[q] + bb));
    });
    __syncthreads();

    // ---- lx: x @ wx^T; gate = sigmoid(lx)*fx -> Gs [64x256]
    stage<512, 16, 520>(Xs, wb + OFF_WX, wave, lane, [&](int nt, int mt, f32x4 v) {
        int c = nt * 16 + l15, r = mt * 16 + rbase;
        float bb = bx[c];
#pragma unroll
        for (int q = 0; q < 4; q++) {
            float g = sigmoidf(v[q] + bb) * bf2f(Fxs[(r + q) * 264 + c]);
            Gs[(r + q) * 264 + c] = f2bf(g);
        }
    });
    __syncthreads();

    // ---- rotated reduction: hidden[b][j] += sum_m gate[t0+m][b][(j + t0 + m + 1) & 255]
    // (roll(h,1)[j] = h[j-1]  =>  hidden[j] = sum_t gate[t][(j - 511 + t) & 255]
    //                                       = sum_t gate[t][(j + t + 1) & 255])
    {
        const int j = tid;
        const int base = (j + t0 + 1) & 255;
        float ph = 0.f;
#pragma unroll 8
        for (int m = 0; m < 64; m++)
            ph += bf2f(Gs[m * 264 + ((base + m) & 255)]);
        atomicAdd(hid + b * 256 + j, ph);
    }
}

// ---------------- output: out = hidden @ wo^T + bo ; also emit hidden ----------
__global__ __launch_bounds__(256) void out_kernel(
    const float* __restrict__ hid, const float* __restrict__ wo,
    const float* __restrict__ bo, float* __restrict__ out)
{
    __shared__ __align__(16) float hrow[256];
    const int b = blockIdx.x, o = threadIdx.x;
    float h = hid[b * 256 + o];
    hrow[o] = h;
    out[65536 + b * 256 + o] = h;          // second output: hidden
    __syncthreads();
    const float4* wrow = (const float4*)(wo + o * 256);
    float s = bo[o];
#pragma unroll 8
    for (int k4 = 0; k4 < 64; k4++) {
        float4 w = wrow[k4];
        float4 hh = *(const float4*)&hrow[k4 * 4];
        s += hh.x * w.x + hh.y * w.y + hh.z * w.z + hh.w * w.w;
    }
    out[b * 256 + o] = s;
}

extern "C" void kernel_launch(void* const* d_in, const int* in_sizes, int n_in,
                              void* d_out, int out_size, void* d_ws, size_t ws_size,
                              hipStream_t stream)
{
    (void)in_sizes; (void)n_in; (void)out_size; (void)ws_size;
    const float* x   = (const float*)d_in[0];
    const float* wm1 = (const float*)d_in[1];
    const float* bm1 = (const float*)d_in[2];
    const float* wm2 = (const float*)d_in[3];
    const float* bm2 = (const float*)d_in[4];
    const float* wm3 = (const float*)d_in[5];
    const float* bm3 = (const float*)d_in[6];
    const float* wm4 = (const float*)d_in[7];
    const float* bm4 = (const float*)d_in[8];
    const float* wm5 = (const float*)d_in[9];
    const float* bm5 = (const float*)d_in[10];
    const float* wx  = (const float*)d_in[11];
    const float* bx  = (const float*)d_in[12];
    const float* wo  = (const float*)d_in[13];
    const float* bo  = (const float*)d_in[14];
    float* out = (float*)d_out;

    unsigned short* wb = (unsigned short*)d_ws;
    float* hid = (float*)((char*)d_ws + (size_t)W_TOTAL * 2);   // fp32 hidden accumulator

    prep_kernel<<<512, 256, 0, stream>>>(wx, wm1, wm2, wm3, wm4, wm5, wb, hid);
    srnn_main<<<2048, 256, 0, stream>>>(x, bm1, bm2, bm3, bm4, bm5, bx, wb, hid);
    out_kernel<<<256, 256, 0, stream>>>(hid, wo, bo, out);
}

// Round 3
// 640.371 us; speedup vs baseline: 1.1713x; 1.1713x over previous
//
#include <hip/hip_runtime.h>

typedef __attribute__((ext_vector_type(8))) short short8;
typedef __attribute__((ext_vector_type(4))) float f32x4;

// bf16 weight workspace layout (element offsets)
#define OFF_WX 0         // [256][512]
#define OFF_W1 131072    // [112][512]  (real 100x512)
#define OFF_W2 188416    // [112][128]  (real 100x100)
#define OFF_W3 202752    // [112][128]  (real 100x100)
#define OFF_W4 217088    // [ 64][128]  (real  50x100)
#define OFF_W5 225280    // [256][ 64]  (real 256x50)
#define W_TOTAL 241664   // bf16 elements

#define TR 32            // timestep rows per block

static __device__ __forceinline__ unsigned short f2bf(float f) {
    unsigned int u = __builtin_bit_cast(unsigned int, f);
    unsigned int r = (u + 0x7fffu + ((u >> 16) & 1u)) >> 16;
    return (unsigned short)r;
}
static __device__ __forceinline__ float bf2f(unsigned short h) {
    unsigned int u = ((unsigned int)h) << 16;
    return __builtin_bit_cast(float, u);
}
static __device__ __forceinline__ float sigmoidf(float z) {
    return 1.f / (1.f + __expf(-z));
}

// ---------------- prep: fp32 weights -> padded bf16 in ws; zero hidden accum ----
__global__ __launch_bounds__(256) void prep_kernel(
    const float* __restrict__ wx, const float* __restrict__ wm1,
    const float* __restrict__ wm2, const float* __restrict__ wm3,
    const float* __restrict__ wm4, const float* __restrict__ wm5,
    unsigned short* __restrict__ wb, float* __restrict__ hid)
{
    const int stride = gridDim.x * blockDim.x;
    for (int idx = blockIdx.x * blockDim.x + threadIdx.x; idx < W_TOTAL; idx += stride) {
        float v;
        if (idx < OFF_W1) {
            v = wx[idx];                                      // exact 256x512
        } else if (idx < OFF_W2) {
            int j = idx - OFF_W1; int n = j >> 9, k = j & 511;
            v = (n < 100) ? wm1[n * 512 + k] : 0.f;
        } else if (idx < OFF_W3) {
            int j = idx - OFF_W2; int n = j >> 7, k = j & 127;
            v = (n < 100 && k < 100) ? wm2[n * 100 + k] : 0.f;
        } else if (idx < OFF_W4) {
            int j = idx - OFF_W3; int n = j >> 7, k = j & 127;
            v = (n < 100 && k < 100) ? wm3[n * 100 + k] : 0.f;
        } else if (idx < OFF_W5) {
            int j = idx - OFF_W4; int n = j >> 7, k = j & 127;
            v = (n < 50 && k < 100) ? wm4[n * 100 + k] : 0.f;
        } else {
            int j = idx - OFF_W5; int n = j >> 6, k = j & 63;
            v = (k < 50) ? wm5[n * 50 + k] : 0.f;
        }
        wb[idx] = f2bf(v);
    }
    for (int idx = blockIdx.x * blockDim.x + threadIdx.x; idx < 65536; idx += stride)
        hid[idx] = 0.f;
}

// ---------------- generic MFMA stage: LDS A [MT*16][APITCH] x global bf16 W [NT*16][KPAD]
// N-tiles split across 4 waves (wave w owns nt = w, w+4, ...). Each wave does all MT
// m-tiles. Epilogue called per (i, nt, mt) with the f32x4 accumulator.
template<int KPAD, int NT, int APITCH, int MT, typename Epi>
static __device__ __forceinline__ void stage(const unsigned short* As,
                                             const unsigned short* __restrict__ Wg,
                                             int wave, int lane, Epi&& epi)
{
    constexpr int NI = (NT + 3) >> 2;
    f32x4 acc[NI][MT];
#pragma unroll
    for (int i = 0; i < NI; i++)
#pragma unroll
        for (int mt = 0; mt < MT; mt++)
            acc[i][mt] = {0.f, 0.f, 0.f, 0.f};

    const int kp  = (lane >> 4) << 3;   // k sub-offset within frag: 0/8/16/24
    const int l15 = lane & 15;

#pragma unroll 4
    for (int k0 = 0; k0 < KPAD; k0 += 32) {
        short8 af[MT];
#pragma unroll
        for (int mt = 0; mt < MT; mt++)
            af[mt] = *(const short8*)(As + (mt * 16 + l15) * APITCH + k0 + kp);
#pragma unroll
        for (int i = 0; i < NI; i++) {
            const int nt = wave + (i << 2);
            if (nt < NT) {
                short8 bf = *(const short8*)(Wg + (nt * 16 + l15) * KPAD + k0 + kp);
#pragma unroll
                for (int mt = 0; mt < MT; mt++)
                    acc[i][mt] = __builtin_amdgcn_mfma_f32_16x16x32_bf16(
                        af[mt], bf, acc[i][mt], 0, 0, 0);
            }
        }
    }
#pragma unroll
    for (int i = 0; i < NI; i++) {
        const int nt = wave + (i << 2);
        if (nt < NT) {
#pragma unroll
            for (int mt = 0; mt < MT; mt++)
                epi(i, nt, mt, acc[i][mt]);
        }
    }
}

// ---------------- main fused kernel: block = (batch b, 32 timesteps t0..t0+31) ----
__global__ __launch_bounds__(256, 3) void srnn_main(
    const float* __restrict__ x,
    const float* __restrict__ b1, const float* __restrict__ b2,
    const float* __restrict__ b3, const float* __restrict__ b4,
    const float* __restrict__ b5, const float* __restrict__ bx,
    const unsigned short* __restrict__ wb, float* __restrict__ hid)
{
    __shared__ __align__(16) unsigned short Xs[TR * 520];       // x tile, bf16, pitch 520
    __shared__ __align__(16) unsigned short ABuf[2 * TR * 136]; // ping-pong acts, pitch 136
    unsigned short* A1 = ABuf;
    unsigned short* A2 = ABuf + TR * 136;
    unsigned short* Gs = ABuf;   // gate tile, pitch 264 (reuses A1+A2 after m5/lx)

    const int tid  = threadIdx.x;
    const int wave = tid >> 6, lane = tid & 63;
    const int blk  = blockIdx.x;
    const int b    = blk >> 4;
    const int t0   = (blk & 15) << 5;
    const int l15  = lane & 15;
    const int rbase = (lane >> 4) << 2;

    // ---- stage x tile (TR rows x 512 fp32 -> bf16 LDS); zero ABuf (pads must be 0)
    for (int f = tid; f < TR * 128; f += 256) {
        int m = f >> 7, c4 = f & 127;
        const float4* src = (const float4*)(x + ((size_t)(t0 + m) * 256 + b) * 512);
        float4 v = src[c4];
        unsigned int p0 = (unsigned int)f2bf(v.x) | ((unsigned int)f2bf(v.y) << 16);
        unsigned int p1 = (unsigned int)f2bf(v.z) | ((unsigned int)f2bf(v.w) << 16);
        *(uint2*)&Xs[m * 520 + (c4 << 2)] = make_uint2(p0, p1);
    }
    for (int i = tid; i < (2 * TR * 136) / 4; i += 256)
        ((uint2*)ABuf)[i] = make_uint2(0u, 0u);
    __syncthreads();

    // ---- m1: x[TRx512] @ w1^T -> relu -> A1 (cols 100..111 zeroed, 112..127 pre-zeroed)
    stage<512, 7, 520, 2>(Xs, wb + OFF_W1, wave, lane, [&](int, int nt, int mt, f32x4 v) {
        int c = nt * 16 + l15, r = mt * 16 + rbase;
        float bb = (c < 100) ? b1[c] : 0.f;
#pragma unroll
        for (int q = 0; q < 4; q++) {
            float val = (c < 100) ? fmaxf(v[q] + bb, 0.f) : 0.f;
            A1[(r + q) * 136 + c] = f2bf(val);
        }
    });
    __syncthreads();

    // ---- m2: A1 @ w2^T -> relu -> A2
    stage<128, 7, 136, 2>(A1, wb + OFF_W2, wave, lane, [&](int, int nt, int mt, f32x4 v) {
        int c = nt * 16 + l15, r = mt * 16 + rbase;
        float bb = (c < 100) ? b2[c] : 0.f;
#pragma unroll
        for (int q = 0; q < 4; q++) {
            float val = (c < 100) ? fmaxf(v[q] + bb, 0.f) : 0.f;
            A2[(r + q) * 136 + c] = f2bf(val);
        }
    });
    __syncthreads();

    // ---- m3: A2 @ w3^T -> relu -> A1
    stage<128, 7, 136, 2>(A2, wb + OFF_W3, wave, lane, [&](int, int nt, int mt, f32x4 v) {
        int c = nt * 16 + l15, r = mt * 16 + rbase;
        float bb = (c < 100) ? b3[c] : 0.f;
#pragma unroll
        for (int q = 0; q < 4; q++) {
            float val = (c < 100) ? fmaxf(v[q] + bb, 0.f) : 0.f;
            A1[(r + q) * 136 + c] = f2bf(val);
        }
    });
    __syncthreads();

    // ---- m4: A1 @ w4^T -> relu -> A2 cols 0..63 (real 50; 50..63 zeroed here)
    stage<128, 4, 136, 2>(A1, wb + OFF_W4, wave, lane, [&](int, int nt, int mt, f32x4 v) {
        int c = nt * 16 + l15, r = mt * 16 + rbase;
        float bb = (c < 50) ? b4[c] : 0.f;
#pragma unroll
        for (int q = 0; q < 4; q++) {
            float val = (c < 50) ? fmaxf(v[q] + bb, 0.f) : 0.f;
            A2[(r + q) * 136 + c] = f2bf(val);
        }
    });
    __syncthreads();

    // ---- m5: A2(K=64) @ w5^T -> sigmoid -> fx kept in REGISTERS (same wave/nt/mt
    //      decomposition as lx below, so no LDS round-trip needed)
    f32x4 fxv[4][2];
    stage<64, 16, 136, 2>(A2, wb + OFF_W5, wave, lane, [&](int i, int nt, int mt, f32x4 v) {
        float bb = b5[nt * 16 + l15];
#pragma unroll
        for (int q = 0; q < 4; q++)
            fxv[i][mt][q] = sigmoidf(v[q] + bb);
    });
    __syncthreads();   // all waves done reading A2 before Gs (aliasing) is written

    // ---- lx: x @ wx^T; gate = sigmoid(lx)*fx -> Gs [TRx256], pitch 264
    stage<512, 16, 520, 2>(Xs, wb + OFF_WX, wave, lane, [&](int i, int nt, int mt, f32x4 v) {
        int c = nt * 16 + l15, r = mt * 16 + rbase;
        float bb = bx[c];
#pragma unroll
        for (int q = 0; q < 4; q++) {
            float g = sigmoidf(v[q] + bb) * fxv[i][mt][q];
            Gs[(r + q) * 264 + c] = f2bf(g);
        }
    });
    __syncthreads();

    // ---- rotated reduction: hidden[b][j] += sum_m gate[t0+m][b][(j + t0 + m + 1) & 255]
    {
        const int j = tid;
        const int base = (j + t0 + 1) & 255;
        float ph = 0.f;
#pragma unroll 8
        for (int m = 0; m < TR; m++)
            ph += bf2f(Gs[m * 264 + ((base + m) & 255)]);
        atomicAdd(hid + b * 256 + j, ph);
    }
}

// ---------------- output: out = hidden @ wo^T + bo ; also emit hidden ----------
__global__ __launch_bounds__(256) void out_kernel(
    const float* __restrict__ hid, const float* __restrict__ wo,
    const float* __restrict__ bo, float* __restrict__ out)
{
    __shared__ __align__(16) float hrow[256];
    const int b = blockIdx.x, o = threadIdx.x;
    float h = hid[b * 256 + o];
    hrow[o] = h;
    out[65536 + b * 256 + o] = h;          // second output: hidden
    __syncthreads();
    const float4* wrow = (const float4*)(wo + o * 256);
    float s = bo[o];
#pragma unroll 8
    for (int k4 = 0; k4 < 64; k4++) {
        float4 w = wrow[k4];
        float4 hh = *(const float4*)&hrow[k4 * 4];
        s += hh.x * w.x + hh.y * w.y + hh.z * w.z + hh.w * w.w;
    }
    out[b * 256 + o] = s;
}

extern "C" void kernel_launch(void* const* d_in, const int* in_sizes, int n_in,
                              void* d_out, int out_size, void* d_ws, size_t ws_size,
                              hipStream_t stream)
{
    (void)in_sizes; (void)n_in; (void)out_size; (void)ws_size;
    const float* x   = (const float*)d_in[0];
    const float* wm1 = (const float*)d_in[1];
    const float* bm1 = (const float*)d_in[2];
    const float* wm2 = (const float*)d_in[3];
    const float* bm2 = (const float*)d_in[4];
    const float* wm3 = (const float*)d_in[5];
    const float* bm3 = (const float*)d_in[6];
    const float* wm4 = (const float*)d_in[7];
    const float* bm4 = (const float*)d_in[8];
    const float* wm5 = (const float*)d_in[9];
    const float* bm5 = (const float*)d_in[10];
    const float* wx  = (const float*)d_in[11];
    const float* bx  = (const float*)d_in[12];
    const float* wo  = (const float*)d_in[13];
    const float* bo  = (const float*)d_in[14];
    float* out = (float*)d_out;

    unsigned short* wb = (unsigned short*)d_ws;
    float* hid = (float*)((char*)d_ws + (size_t)W_TOTAL * 2);   // fp32 hidden accumulator

    prep_kernel<<<512, 256, 0, stream>>>(wx, wm1, wm2, wm3, wm4, wm5, wb, hid);
    srnn_main<<<4096, 256, 0, stream>>>(x, bm1, bm2, bm3, bm4, bm5, bx, wb, hid);
    out_kernel<<<256, 256, 0, stream>>>(hid, wo, bo, out);
}

// Round 4
// 610.316 us; speedup vs baseline: 1.2290x; 1.0492x over previous
//
#include <hip/hip_runtime.h>

typedef __attribute__((ext_vector_type(8))) short short8;
typedef __attribute__((ext_vector_type(4))) float f32x4;

// bf16 weight workspace layout (element offsets) — all N padded to x4 16-tiles
#define OFF_WX 0         // [256][512]
#define OFF_W1 131072    // [128][512]  (real 100x512)
#define OFF_W2 196608    // [128][128]  (real 100x100)
#define OFF_W3 212992    // [128][128]  (real 100x100)
#define OFF_W4 229376    // [ 64][128]  (real  50x100)
#define OFF_W5 237568    // [256][ 64]  (real 256x50)
#define W_TOTAL 253952   // bf16 elements
#define TR 32            // timestep rows per block

static __device__ __forceinline__ unsigned short f2bf(float f) {
    unsigned int u = __builtin_bit_cast(unsigned int, f);
    unsigned int r = (u + 0x7fffu + ((u >> 16) & 1u)) >> 16;
    return (unsigned short)r;
}
static __device__ __forceinline__ float bf2f(unsigned short h) {
    unsigned int u = ((unsigned int)h) << 16;
    return __builtin_bit_cast(float, u);
}
static __device__ __forceinline__ float sigmoidf(float z) {
    return 1.f / (1.f + __expf(-z));
}
// swizzled bf16 store into a [rows][128] activation tile (8-elem xor-swizzle)
static __device__ __forceinline__ void stA(unsigned short* dst, int r, int c, float v) {
    dst[(r << 7) + (((c >> 3) ^ (r & 7)) << 3) + (c & 7)] = f2bf(v);
}

// ---------------- prep: fp32 weights -> padded bf16 in ws; zero hidden accum ----
__global__ __launch_bounds__(256) void prep_kernel(
    const float* __restrict__ wx, const float* __restrict__ wm1,
    const float* __restrict__ wm2, const float* __restrict__ wm3,
    const float* __restrict__ wm4, const float* __restrict__ wm5,
    unsigned short* __restrict__ wb, float* __restrict__ hid)
{
    const int stride = gridDim.x * blockDim.x;
    for (int idx = blockIdx.x * blockDim.x + threadIdx.x; idx < W_TOTAL; idx += stride) {
        float v;
        if (idx < OFF_W1) {
            v = wx[idx];                                      // exact 256x512
        } else if (idx < OFF_W2) {
            int j = idx - OFF_W1; int n = j >> 9, k = j & 511;
            v = (n < 100) ? wm1[n * 512 + k] : 0.f;
        } else if (idx < OFF_W3) {
            int j = idx - OFF_W2; int n = j >> 7, k = j & 127;
            v = (n < 100 && k < 100) ? wm2[n * 100 + k] : 0.f;
        } else if (idx < OFF_W4) {
            int j = idx - OFF_W3; int n = j >> 7, k = j & 127;
            v = (n < 100 && k < 100) ? wm3[n * 100 + k] : 0.f;
        } else if (idx < OFF_W5) {
            int j = idx - OFF_W4; int n = j >> 7, k = j & 127;
            v = (n < 50 && k < 100) ? wm4[n * 100 + k] : 0.f;
        } else {
            int j = idx - OFF_W5; int n = j >> 6, k = j & 63;
            v = (k < 50) ? wm5[n * 50 + k] : 0.f;
        }
        wb[idx] = f2bf(v);
    }
    for (int idx = blockIdx.x * blockDim.x + threadIdx.x; idx < 65536; idx += stride)
        hid[idx] = 0.f;
}

// ---------------- generic MFMA stage over a swizzled [32][128] LDS A-tile -------
// B pitch = KLOOP. NI n-tiles per wave (nt = wave + 4i), MT=2 fixed. Branch-free.
template<int KLOOP, int NI, typename Epi>
static __device__ __forceinline__ void stageS(const unsigned short* As,
                                              const unsigned short* __restrict__ Wg,
                                              int wave, int lane, Epi&& epi)
{
    f32x4 acc[NI][2];
#pragma unroll
    for (int i = 0; i < NI; i++) { acc[i][0] = {0,0,0,0}; acc[i][1] = {0,0,0,0}; }
    const int kp  = (lane >> 4) << 3;
    const int l15 = lane & 15;
#pragma unroll
    for (int k0 = 0; k0 < KLOOP; k0 += 32) {
        const int kb = (k0 >> 3) + (lane >> 4);
        short8 af[2];
#pragma unroll
        for (int mt = 0; mt < 2; mt++) {
            const int rm = mt * 16 + l15;
            af[mt] = *(const short8*)(As + (rm << 7) + ((kb ^ (rm & 7)) << 3));
        }
#pragma unroll
        for (int i = 0; i < NI; i++) {
            const int nt = wave + (i << 2);
            short8 bf = *(const short8*)(Wg + (nt * 16 + l15) * KLOOP + k0 + kp);
#pragma unroll
            for (int mt = 0; mt < 2; mt++)
                acc[i][mt] = __builtin_amdgcn_mfma_f32_16x16x32_bf16(
                    af[mt], bf, acc[i][mt], 0, 0, 0);
        }
    }
#pragma unroll
    for (int i = 0; i < NI; i++)
#pragma unroll
        for (int mt = 0; mt < 2; mt++)
            epi(i, wave + (i << 2), mt, acc[i][mt]);
}

// ---------------- main fused kernel: block = (batch b, 32 timesteps t0..t0+31) ----
__global__ __launch_bounds__(256, 4) void srnn_main(
    const float* __restrict__ x,
    const float* __restrict__ b1, const float* __restrict__ b2,
    const float* __restrict__ b3, const float* __restrict__ b4,
    const float* __restrict__ b5, const float* __restrict__ bx,
    const unsigned short* __restrict__ wb, float* __restrict__ hid)
{
    __shared__ __align__(16) unsigned short Xs[TR * 512];   // swizzled x tile (32 KB)
    __shared__ __align__(16) unsigned short A1[TR * 128];   // swizzled act tile (8 KB)
    unsigned short* A2 = Xs;           // [32][128] swizzled, aliases Xs after pass 1
    unsigned short* Gs = Xs + 4096;    // [32][256] plain pitch-256, aliases Xs after pass 1

    const int tid  = threadIdx.x;
    const int wave = tid >> 6, lane = tid & 63;
    const int blk  = blockIdx.x;
    const int b    = blk >> 4;
    const int t0   = (blk & 15) << 5;
    const int l15  = lane & 15;
    const int rb   = (lane >> 4) << 2;
    const int kp   = (lane >> 4) << 3;

    // ---- stage x tile: batch 16 float4 HBM loads, then convert+swizzled store
    {
        const int m0 = tid >> 7, c4 = tid & 127;
        const float* xbase = x + ((size_t)(t0 + m0) * 256 + b) * 512 + (c4 << 2);
        float4 xr[16];
#pragma unroll
        for (int it = 0; it < 16; it++)
            xr[it] = *(const float4*)(xbase + (size_t)it * 262144);   // 2 timesteps apart
        const int blk8 = c4 >> 1, halfoff = (c4 & 1) << 2;
#pragma unroll
        for (int it = 0; it < 16; it++) {
            const int m = m0 + 2 * it;
            unsigned int p0 = (unsigned int)f2bf(xr[it].x) | ((unsigned int)f2bf(xr[it].y) << 16);
            unsigned int p1 = (unsigned int)f2bf(xr[it].z) | ((unsigned int)f2bf(xr[it].w) << 16);
            *(uint2*)&Xs[(m << 9) + ((blk8 ^ (m & 7)) << 3) + halfoff] = make_uint2(p0, p1);
        }
    }
    __syncthreads();

    // ---- fused pass 1: m1 (NI=2) and lx (NI=4) share Xs A-fragments, K=512
    f32x4 am1[2][2], alx[4][2];
#pragma unroll
    for (int i = 0; i < 2; i++) { am1[i][0] = {0,0,0,0}; am1[i][1] = {0,0,0,0}; }
#pragma unroll
    for (int i = 0; i < 4; i++) { alx[i][0] = {0,0,0,0}; alx[i][1] = {0,0,0,0}; }
    {
        const unsigned short* W1 = wb + OFF_W1;
        const unsigned short* WX = wb + OFF_WX;
#pragma unroll 4
        for (int k0 = 0; k0 < 512; k0 += 32) {
            const int kb = (k0 >> 3) + (lane >> 4);
            short8 af[2];
#pragma unroll
            for (int mt = 0; mt < 2; mt++) {
                const int rm = mt * 16 + l15;
                af[mt] = *(const short8*)(Xs + (rm << 9) + ((kb ^ (rm & 7)) << 3));
            }
#pragma unroll
            for (int i = 0; i < 2; i++) {
                short8 bf = *(const short8*)(W1 + ((wave + (i << 2)) * 16 + l15) * 512 + k0 + kp);
                am1[i][0] = __builtin_amdgcn_mfma_f32_16x16x32_bf16(af[0], bf, am1[i][0], 0, 0, 0);
                am1[i][1] = __builtin_amdgcn_mfma_f32_16x16x32_bf16(af[1], bf, am1[i][1], 0, 0, 0);
            }
#pragma unroll
            for (int i = 0; i < 4; i++) {
                short8 bf = *(const short8*)(WX + ((wave + (i << 2)) * 16 + l15) * 512 + k0 + kp);
                alx[i][0] = __builtin_amdgcn_mfma_f32_16x16x32_bf16(af[0], bf, alx[i][0], 0, 0, 0);
                alx[i][1] = __builtin_amdgcn_mfma_f32_16x16x32_bf16(af[1], bf, alx[i][1], 0, 0, 0);
            }
        }
        // epilogue m1 -> A1 (relu); alx stays in registers through m2..m5
#pragma unroll
        for (int i = 0; i < 2; i++) {
            const int c = (wave + (i << 2)) * 16 + l15;
            const float bb = (c < 100) ? b1[c] : 0.f;
#pragma unroll
            for (int mt = 0; mt < 2; mt++)
#pragma unroll
                for (int q = 0; q < 4; q++)
                    stA(A1, mt * 16 + rb + q, c,
                        (c < 100) ? fmaxf(am1[i][mt][q] + bb, 0.f) : 0.f);
        }
    }
    __syncthreads();

    // ---- m2: A1 -> A2 (aliases dead Xs)
    stageS<128, 2>(A1, wb + OFF_W2, wave, lane, [&](int, int nt, int mt, f32x4 v) {
        const int c = nt * 16 + l15;
        const float bb = (c < 100) ? b2[c] : 0.f;
#pragma unroll
        for (int q = 0; q < 4; q++)
            stA(A2, mt * 16 + rb + q, c, (c < 100) ? fmaxf(v[q] + bb, 0.f) : 0.f);
    });
    __syncthreads();

    // ---- m3: A2 -> A1
    stageS<128, 2>(A2, wb + OFF_W3, wave, lane, [&](int, int nt, int mt, f32x4 v) {
        const int c = nt * 16 + l15;
        const float bb = (c < 100) ? b3[c] : 0.f;
#pragma unroll
        for (int q = 0; q < 4; q++)
            stA(A1, mt * 16 + rb + q, c, (c < 100) ? fmaxf(v[q] + bb, 0.f) : 0.f);
    });
    __syncthreads();

    // ---- m4: A1 -> A2 (64 cols, real 50)
    stageS<128, 1>(A1, wb + OFF_W4, wave, lane, [&](int, int nt, int mt, f32x4 v) {
        const int c = nt * 16 + l15;
        const float bb = (c < 50) ? b4[c] : 0.f;
#pragma unroll
        for (int q = 0; q < 4; q++)
            stA(A2, mt * 16 + rb + q, c, (c < 50) ? fmaxf(v[q] + bb, 0.f) : 0.f);
    });
    __syncthreads();

    // ---- m5 (K=64): gate = sigmoid(m5)+ * sigmoid(lx) -> Gs [32][256]
    stageS<64, 4>(A2, wb + OFF_W5, wave, lane, [&](int i, int nt, int mt, f32x4 v) {
        const int c = nt * 16 + l15;
        const float bb5 = b5[c], bbx = bx[c];
#pragma unroll
        for (int q = 0; q < 4; q++) {
            const float g = sigmoidf(v[q] + bb5) * sigmoidf(alx[i][mt][q] + bbx);
            Gs[(mt * 16 + rb + q) * 256 + c] = f2bf(g);
        }
    });
    __syncthreads();

    // ---- rotated reduction: hidden[b][j] += sum_m gate[t0+m][b][(j + t0 + m + 1) & 255]
    {
        const int j = tid;
        const int base = (j + t0 + 1) & 255;
        float ph = 0.f;
#pragma unroll
        for (int m = 0; m < TR; m++)
            ph += bf2f(Gs[(m << 8) + ((base + m) & 255)]);
        atomicAdd(hid + b * 256 + j, ph);
    }
}

// ---------------- output: out = hidden @ wo^T + bo ; also emit hidden ----------
__global__ __launch_bounds__(256) void out_kernel(
    const float* __restrict__ hid, const float* __restrict__ wo,
    const float* __restrict__ bo, float* __restrict__ out)
{
    __shared__ __align__(16) float hrow[256];
    const int b = blockIdx.x, o = threadIdx.x;
    float h = hid[b * 256 + o];
    hrow[o] = h;
    out[65536 + b * 256 + o] = h;          // second output: hidden
    __syncthreads();
    const float4* wrow = (const float4*)(wo + o * 256);
    float s = bo[o];
#pragma unroll 8
    for (int k4 = 0; k4 < 64; k4++) {
        float4 w = wrow[k4];
        float4 hh = *(const float4*)&hrow[k4 * 4];
        s += hh.x * w.x + hh.y * w.y + hh.z * w.z + hh.w * w.w;
    }
    out[b * 256 + o] = s;
}

extern "C" void kernel_launch(void* const* d_in, const int* in_sizes, int n_in,
                              void* d_out, int out_size, void* d_ws, size_t ws_size,
                              hipStream_t stream)
{
    (void)in_sizes; (void)n_in; (void)out_size; (void)ws_size;
    const float* x   = (const float*)d_in[0];
    const float* wm1 = (const float*)d_in[1];
    const float* bm1 = (const float*)d_in[2];
    const float* wm2 = (const float*)d_in[3];
    const float* bm2 = (const float*)d_in[4];
    const float* wm3 = (const float*)d_in[5];
    const float* bm3 = (const float*)d_in[6];
    const float* wm4 = (const float*)d_in[7];
    const float* bm4 = (const float*)d_in[8];
    const float* wm5 = (const float*)d_in[9];
    const float* bm5 = (const float*)d_in[10];
    const float* wx  = (const float*)d_in[11];
    const float* bx  = (const float*)d_in[12];
    const float* wo  = (const float*)d_in[13];
    const float* bo  = (const float*)d_in[14];
    float* out = (float*)d_out;

    unsigned short* wb = (unsigned short*)d_ws;
    float* hid = (float*)((char*)d_ws + (size_t)W_TOTAL * 2);   // fp32 hidden accumulator

    prep_kernel<<<512, 256, 0, stream>>>(wx, wm1, wm2, wm3, wm4, wm5, wb, hid);
    srnn_main<<<4096, 256, 0, stream>>>(x, bm1, bm2, bm3, bm4, bm5, bx, wb, hid);
    out_kernel<<<256, 256, 0, stream>>>(hid, wo, bo, out);
}